// Round 9
// baseline (420.017 us; speedup 1.0000x reference)
//
#include <hip/hip_runtime.h>
#include <hip/hip_bf16.h>
#include <math.h>

typedef __attribute__((ext_vector_type(8))) short bf16x8;
typedef __attribute__((ext_vector_type(4))) float f32x4;
typedef __attribute__((ext_vector_type(16))) float f32x16;

__device__ __forceinline__ unsigned short f2bf(float f) {
  union { float f; unsigned int u; } v; v.f = f;
  unsigned int u = v.u;
  u += 0x7fffu + ((u >> 16) & 1u);   // RNE
  return (unsigned short)(u >> 16);
}

__device__ __forceinline__ float bf2f(unsigned short h) {
  union { unsigned int u; float f; } v; v.u = ((unsigned int)h) << 16;
  return v.f;
}

// async global->LDS, 16B per lane; LDS dest = wave-uniform base + lane*16
__device__ __forceinline__ void gl2l16(const unsigned short* g, unsigned short* l) {
  __builtin_amdgcn_global_load_lds(
      (const __attribute__((address_space(1))) unsigned int*)g,
      (__attribute__((address_space(3))) unsigned int*)l, 16, 0, 0);
}

// fast tanh-form GELU: v * sigmoid(1.5957691*v + 0.0713548*v^3)
__device__ __forceinline__ float gelu_fast(float v) {
  float arg = v * (1.59576912f + 0.07135481f * v * v);
  return v / (1.f + __expf(-arg));
}

// ---------------- prologue: weight conversions (blocks 0..6911) + ada (6912..6983) ----
__global__ __launch_bounds__(256) void k_prologue(
    const float4* __restrict__ s0, ushort4* __restrict__ d0,
    const float4* __restrict__ s1, ushort4* __restrict__ d1,
    const float4* __restrict__ s2, ushort4* __restrict__ d2,
    const float4* __restrict__ s3, ushort4* __restrict__ d3,
    const float* __restrict__ c, const float* __restrict__ ada_w,
    const float* __restrict__ ada_b, float* __restrict__ ada) {
  __shared__ float smem[8 * 768 + 4 * 64 * 8];
  const int t = threadIdx.x;
  const int id = blockIdx.x;
  if (id < 6912) {
    int i = id * 256 + t;
    const float4* s; ushort4* d; int off;
    if (i < 442368) { s = s0; d = d0; off = i; }
    else if (i < 589824) { s = s1; d = d1; off = i - 442368; }
    else if (i < 1179648) { s = s2; d = d2; off = i - 589824; }
    else { s = s3; d = d3; off = i - 1179648; }
    float4 f = s[off];
    ushort4 o;
    o.x = f2bf(f.x); o.y = f2bf(f.y); o.z = f2bf(f.z); o.w = f2bf(f.w);
    d[off] = o;
    return;
  }
  // ---- ada path ----
  float* sc = smem;
  float* red = smem + 8 * 768;  // [4][64][8]
  for (int i = t; i < 8 * 768; i += 256) {
    float v = c[i];
    sc[i] = v / (1.f + __expf(-v));
  }
  __syncthreads();
  const int cl = t & 63, ks = t >> 6;
  const int col = (id - 6912) * 64 + cl;
  float acc[8];
#pragma unroll
  for (int b = 0; b < 8; b++) acc[b] = 0.f;
  const float* wr = ada_w + (size_t)col * 768 + ks * 192;
  for (int k = 0; k < 192; k += 4) {
    float4 w = *(const float4*)&wr[k];
    const int kk = ks * 192 + k;
#pragma unroll
    for (int b = 0; b < 8; b++) {
      acc[b] += sc[b * 768 + kk] * w.x + sc[b * 768 + kk + 1] * w.y +
                sc[b * 768 + kk + 2] * w.z + sc[b * 768 + kk + 3] * w.w;
    }
  }
#pragma unroll
  for (int b = 0; b < 8; b++) red[(ks * 64 + cl) * 8 + b] = acc[b];
  __syncthreads();
  if (ks == 0) {
    const float bj = ada_b[col];
#pragma unroll
    for (int b = 0; b < 8; b++)
      ada[b * 4608 + col] = red[(0 * 64 + cl) * 8 + b] + red[(1 * 64 + cl) * 8 + b] +
                            red[(2 * 64 + cl) * 8 + b] + red[(3 * 64 + cl) * 8 + b] + bj;
  }
}

// ---------------- LayerNorm + modulate -> bf16 (fp32 or bf16 input) ----------------
template <bool BF>
__global__ __launch_bounds__(256) void k_ln_mod(const void* __restrict__ xin,
                                                const float* __restrict__ ada,
                                                int sh_off, int sc_off,
                                                unsigned short* __restrict__ h) {
  const int row = blockIdx.x, t = threadIdx.x, b = row >> 10;
  float v0, v1, v2;
  if (BF) {
    const unsigned short* xr = (const unsigned short*)xin + (size_t)row * 768;
    v0 = bf2f(xr[t]); v1 = bf2f(xr[t + 256]); v2 = bf2f(xr[t + 512]);
  } else {
    const float* xr = (const float*)xin + (size_t)row * 768;
    v0 = xr[t]; v1 = xr[t + 256]; v2 = xr[t + 512];
  }
  float s = v0 + v1 + v2;
  float ss = v0 * v0 + v1 * v1 + v2 * v2;
#pragma unroll
  for (int m = 1; m < 64; m <<= 1) {
    s += __shfl_xor(s, m);
    ss += __shfl_xor(ss, m);
  }
  __shared__ float red[8];
  if ((t & 63) == 0) { red[t >> 6] = s; red[4 + (t >> 6)] = ss; }
  __syncthreads();
  const float S = red[0] + red[1] + red[2] + red[3];
  const float SS = red[4] + red[5] + red[6] + red[7];
  const float mean = S * (1.f / 768.f);
  const float var = SS * (1.f / 768.f) - mean * mean;
  const float inv = rsqrtf(var + 1e-6f);
  const float* sh = ada + b * 4608 + sh_off;
  const float* scp = ada + b * 4608 + sc_off;
  unsigned short* hr = h + (size_t)row * 768;
  float vv[3] = {v0, v1, v2};
#pragma unroll
  for (int i = 0; i < 3; i++) {
    int cx = t + i * 256;
    float hh = (vv[i] - mean) * inv;
    hh = hh * (1.f + scp[cx]) + sh[cx];
    hr[cx] = f2bf(hh);
  }
}

// ---------------- GEMM v16: 16x16x32 MFMA (R7-proven: 0 conflicts, 16 indep accs) ----
// Used for qkv (EPI 0) — 32x32 variant measured slower there (R8: 72 vs ~58 us).
template <int EPI, int TN>
__global__ __launch_bounds__(256) void k_gemm16(const unsigned short* __restrict__ A,
                                                const unsigned short* __restrict__ B,
                                                const float* __restrict__ bias,
                                                int N, int K, int nbx,
                                                const float* __restrict__ residf,
                                                const unsigned short* __restrict__ residb,
                                                const float* __restrict__ ada, int goff,
                                                float* __restrict__ outf,
                                                unsigned short* __restrict__ outb,
                                                unsigned short* __restrict__ vt) {
  constexpr int MI = (TN == 128) ? 4 : 2;
  __shared__ __align__(16) unsigned short Asm[2][128 * 32];
  __shared__ __align__(16) unsigned short Bsm[2][TN * 32];
  const int t = threadIdx.x;
  const int w = t >> 6, lane = t & 63, l = lane & 15, qd = lane >> 4;

  const int id = blockIdx.x;
  const int xcd = id & 7, jj = id >> 3;
  const int jm = jj / nbx;
  const int bmi = xcd + (jm << 3);
  const int bni = jj - jm * nbx;
  const int bn = bni * TN, bm = bmi * 128;

  const int wm = (TN == 128) ? (w >> 1) * 64 : w * 32;
  const int wn = (TN == 128) ? (w & 1) * 64 : 0;

  const int srow = t >> 2;
  const int scol = ((t & 3) ^ ((srow >> 1) & 3)) * 8;
  const unsigned short* Ap0 = A + (size_t)(bm + srow) * K + scol;
  const unsigned short* Ap1 = A + (size_t)(bm + 64 + srow) * K + scol;
  const unsigned short* Bp0 = B + (size_t)(bn + srow) * K + scol;
  const unsigned short* Bp1 = B + (size_t)(bn + 64 + srow) * K + scol;

  f32x4 acc[MI][4];
#pragma unroll
  for (int i = 0; i < MI; i++)
#pragma unroll
    for (int j = 0; j < 4; j++) acc[i][j] = {0.f, 0.f, 0.f, 0.f};

  const int swz = (l >> 1) & 3;

  for (int k0 = 0; k0 < K; k0 += 64) {
#pragma unroll
    for (int s = 0; s < 2; s++) {
      gl2l16(Ap0 + k0 + 32 * s, &Asm[s][w * 512]);
      gl2l16(Ap1 + k0 + 32 * s, &Asm[s][2048 + w * 512]);
      gl2l16(Bp0 + k0 + 32 * s, &Bsm[s][w * 512]);
      if (TN == 128) gl2l16(Bp1 + k0 + 32 * s, &Bsm[s][2048 + w * 512]);
    }
    __syncthreads();
#pragma unroll
    for (int s = 0; s < 2; s++) {
      bf16x8 af[MI], bfr[4];
#pragma unroll
      for (int i = 0; i < MI; i++)
        af[i] = *(const bf16x8*)&Asm[s][(wm + i * 16 + l) * 32 + ((qd ^ swz) << 3)];
#pragma unroll
      for (int j = 0; j < 4; j++)
        bfr[j] = *(const bf16x8*)&Bsm[s][(wn + j * 16 + l) * 32 + ((qd ^ swz) << 3)];
#pragma unroll
      for (int i = 0; i < MI; i++)
#pragma unroll
        for (int j = 0; j < 4; j++)
          acc[i][j] = __builtin_amdgcn_mfma_f32_16x16x32_bf16(af[i], bfr[j], acc[i][j], 0, 0, 0);
    }
    __syncthreads();
  }

#pragma unroll
  for (int i = 0; i < MI; i++) {
#pragma unroll
    for (int j = 0; j < 4; j++) {
      const int gn = bn + wn + j * 16 + l;
      const float bv = bias[gn];
#pragma unroll
      for (int r = 0; r < 4; r++) {
        const int gm = bm + wm + i * 16 + qd * 4 + r;
        float v = acc[i][j][r] + bv;
        if (EPI == 0) {
          if (gn < 1536) {
            outb[(size_t)gm * 1536 + gn] = f2bf(v);
          } else {
            const int hh = (gn - 1536) >> 6, dd = (gn - 1536) & 63;
            const int bb = gm >> 10, nn = gm & 1023;
            vt[(((size_t)bb * 12 + hh) * 64 + dd) * 1024 + nn] = f2bf(v);
          }
        } else if (EPI == 1) {
          const int bb = gm >> 10;
          const float g = ada[bb * 4608 + goff + gn];
          outb[(size_t)gm * 768 + gn] =
              f2bf(residf[(size_t)gm * 768 + gn] + g * v);
        } else if (EPI == 2) {
          outb[(size_t)gm * N + gn] = f2bf(gelu_fast(v));
        } else {
          const int bb = gm >> 10;
          const float g = ada[bb * 4608 + goff + gn];
          outf[(size_t)gm * 768 + gn] =
              bf2f(residb[(size_t)gm * 768 + gn]) + g * v;
        }
      }
    }
  }
}

// ---------------- GEMM v32: 32x32x16 MFMA (R8: won on proj/fc1/fc2) ----------------
template <int EPI, int TN>
__global__ __launch_bounds__(256) void k_gemm32(const unsigned short* __restrict__ A,
                                                const unsigned short* __restrict__ B,
                                                const float* __restrict__ bias,
                                                int N, int K, int nbx,
                                                const float* __restrict__ residf,
                                                const unsigned short* __restrict__ residb,
                                                const float* __restrict__ ada, int goff,
                                                float* __restrict__ outf,
                                                unsigned short* __restrict__ outb,
                                                unsigned short* __restrict__ vt) {
  constexpr int NMT = (TN == 128) ? 2 : 1;   // 32-row m-tiles per wave
  __shared__ __align__(16) unsigned short Asm[2][128 * 32];
  __shared__ __align__(16) unsigned short Bsm[2][TN * 32];
  const int t = threadIdx.x;
  const int w = t >> 6, lane = t & 63;
  const int ln31 = lane & 31, half = lane >> 5;

  const int id = blockIdx.x;
  const int xcd = id & 7, jj = id >> 3;
  const int jm = jj / nbx;
  const int bmi = xcd + (jm << 3);
  const int bni = jj - jm * nbx;
  const int bn = bni * TN, bm = bmi * 128;

  const int wm = (TN == 128) ? (w >> 1) * 64 : w * 32;
  const int wn = (TN == 128) ? (w & 1) * 64 : 0;

  const int srow = t >> 2;
  const int scol = ((t & 3) ^ ((srow >> 1) & 3)) * 8;
  const unsigned short* Ap0 = A + (size_t)(bm + srow) * K + scol;
  const unsigned short* Ap1 = A + (size_t)(bm + 64 + srow) * K + scol;
  const unsigned short* Bp0 = B + (size_t)(bn + srow) * K + scol;
  const unsigned short* Bp1 = B + (size_t)(bn + 64 + srow) * K + scol;

  f32x16 acc[NMT][2];
#pragma unroll
  for (int i = 0; i < NMT; i++)
#pragma unroll
    for (int j = 0; j < 2; j++)
#pragma unroll
      for (int r = 0; r < 16; r++) acc[i][j][r] = 0.f;

  const int swz = (ln31 >> 1) & 3;

  for (int k0 = 0; k0 < K; k0 += 64) {
#pragma unroll
    for (int s = 0; s < 2; s++) {
      gl2l16(Ap0 + k0 + 32 * s, &Asm[s][w * 512]);
      gl2l16(Ap1 + k0 + 32 * s, &Asm[s][2048 + w * 512]);
      gl2l16(Bp0 + k0 + 32 * s, &Bsm[s][w * 512]);
      if (TN == 128) gl2l16(Bp1 + k0 + 32 * s, &Bsm[s][2048 + w * 512]);
    }
    __syncthreads();
#pragma unroll
    for (int s = 0; s < 4; s++) {          // 4 k-steps of 16
      const int sb = s >> 1;
      const int chunk = (s & 1) * 2 + half;
      const int coff = ((chunk ^ swz) << 3);
      bf16x8 af[NMT], bfr[2];
#pragma unroll
      for (int i = 0; i < NMT; i++)
        af[i] = *(const bf16x8*)&Asm[sb][(wm + i * 32 + ln31) * 32 + coff];
#pragma unroll
      for (int j = 0; j < 2; j++)
        bfr[j] = *(const bf16x8*)&Bsm[sb][(wn + j * 32 + ln31) * 32 + coff];
#pragma unroll
      for (int i = 0; i < NMT; i++)
#pragma unroll
        for (int j = 0; j < 2; j++)
          acc[i][j] = __builtin_amdgcn_mfma_f32_32x32x16_bf16(af[i], bfr[j], acc[i][j], 0, 0, 0);
    }
    __syncthreads();
  }

#pragma unroll
  for (int i = 0; i < NMT; i++) {
#pragma unroll
    for (int j = 0; j < 2; j++) {
      const int gn = bn + wn + j * 32 + ln31;
      const float bv = bias[gn];
#pragma unroll
      for (int reg = 0; reg < 16; reg++) {
        const int gm = bm + wm + i * 32 + (reg & 3) + 8 * (reg >> 2) + 4 * half;
        float v = acc[i][j][reg] + bv;
        if (EPI == 1) {
          const int bb = gm >> 10;
          const float g = ada[bb * 4608 + goff + gn];
          outb[(size_t)gm * 768 + gn] =
              f2bf(residf[(size_t)gm * 768 + gn] + g * v);
        } else if (EPI == 2) {
          outb[(size_t)gm * N + gn] = f2bf(gelu_fast(v));
        } else {
          const int bb = gm >> 10;
          const float g = ada[bb * 4608 + goff + gn];
          outf[(size_t)gm * 768 + gn] =
              bf2f(residb[(size_t)gm * 768 + gn]) + g * v;
        }
      }
    }
  }
}

// ---------------- Attention: 128 Q rows per block, no-max softmax ----------------
// qk: (8192,1536) bf16 [q|k]; vt: (8,12,64,1024) bf16; o: (8192,768) bf16
__global__ __launch_bounds__(256) void k_attn(const unsigned short* __restrict__ qk,
                                              const unsigned short* __restrict__ vt,
                                              unsigned short* __restrict__ o) {
  __shared__ __align__(16) unsigned short Ksm[64 * 64];
  __shared__ __align__(16) unsigned short Vsm[64 * 64];
  __shared__ __align__(16) unsigned short Psm[128 * 76];
  const int t = threadIdx.x;
  const int qb = blockIdx.x, h = blockIdx.y, b = blockIdx.z;
  const int w = t >> 6, lane = t & 63, l = lane & 15, qd = lane >> 4;

  const size_t qrow0 = (size_t)(b * 1024 + qb * 128 + w * 32 + l);
  bf16x8 qf[2][2];
#pragma unroll
  for (int mt = 0; mt < 2; mt++)
#pragma unroll
    for (int ks = 0; ks < 2; ks++)
      qf[mt][ks] = *(const bf16x8*)&qk[(qrow0 + mt * 16) * 1536 + h * 64 + ks * 32 + qd * 8];

  f32x4 oacc[2][4];
  float rsum[2][4];
#pragma unroll
  for (int mt = 0; mt < 2; mt++)
#pragma unroll
    for (int j2 = 0; j2 < 4; j2++) { oacc[mt][j2] = {0.f, 0.f, 0.f, 0.f}; rsum[mt][j2] = 0.f; }

  const size_t kbase = (size_t)b * 1024 * 1536 + 768 + h * 64;
  const size_t vbase = ((size_t)(b * 12 + h)) * 64 * 1024;

  const int srw8 = lane >> 3, schk = lane & 7;
  const int swz = (l >> 1) & 7;

  for (int k0 = 0; k0 < 1024; k0 += 64) {
#pragma unroll
    for (int c = 0; c < 2; c++) {
      const int row = c * 32 + w * 8 + srw8;
      const int sc = (schk ^ ((row >> 1) & 7)) * 8;
      gl2l16(&qk[kbase + (size_t)(k0 + row) * 1536 + sc], &Ksm[(c * 32 + w * 8) * 64]);
      gl2l16(&vt[vbase + (size_t)row * 1024 + k0 + sc], &Vsm[(c * 32 + w * 8) * 64]);
    }
    __syncthreads();

    bf16x8 kf[4][2];
#pragma unroll
    for (int ct = 0; ct < 4; ct++)
#pragma unroll
      for (int ks = 0; ks < 2; ks++)
        kf[ct][ks] = *(const bf16x8*)&Ksm[(ct * 16 + l) * 64 + (((ks * 4 + qd) ^ swz) << 3)];

#pragma unroll
    for (int mt = 0; mt < 2; mt++) {
      f32x4 s[4];
#pragma unroll
      for (int ct = 0; ct < 4; ct++) {
        f32x4 a = {0.f, 0.f, 0.f, 0.f};
        a = __builtin_amdgcn_mfma_f32_16x16x32_bf16(qf[mt][0], kf[ct][0], a, 0, 0, 0);
        a = __builtin_amdgcn_mfma_f32_16x16x32_bf16(qf[mt][1], kf[ct][1], a, 0, 0, 0);
        s[ct] = a;
      }
#pragma unroll
      for (int ct = 0; ct < 4; ct++) {
#pragma unroll
        for (int r = 0; r < 4; r++) {
          float p = __expf(s[ct][r] * 0.125f);
          rsum[mt][r] += p;
          Psm[(w * 32 + mt * 16 + qd * 4 + r) * 76 + ct * 16 + l] = f2bf(p);
        }
      }
    }

    bf16x8 vf[4][2];
#pragma unroll
    for (int dt = 0; dt < 4; dt++)
#pragma unroll
      for (int ks = 0; ks < 2; ks++)
        vf[dt][ks] = *(const bf16x8*)&Vsm[(dt * 16 + l) * 64 + (((ks * 4 + qd) ^ swz) << 3)];
#pragma unroll
    for (int mt = 0; mt < 2; mt++) {
      bf16x8 pf0 = *(const bf16x8*)&Psm[(w * 32 + mt * 16 + l) * 76 + qd * 8];
      bf16x8 pf1 = *(const bf16x8*)&Psm[(w * 32 + mt * 16 + l) * 76 + 32 + qd * 8];
#pragma unroll
      for (int dt = 0; dt < 4; dt++) {
        oacc[mt][dt] = __builtin_amdgcn_mfma_f32_16x16x32_bf16(pf0, vf[dt][0], oacc[mt][dt], 0, 0, 0);
        oacc[mt][dt] = __builtin_amdgcn_mfma_f32_16x16x32_bf16(pf1, vf[dt][1], oacc[mt][dt], 0, 0, 0);
      }
    }
    __syncthreads();
  }

#pragma unroll
  for (int mt = 0; mt < 2; mt++)
#pragma unroll
    for (int r = 0; r < 4; r++) {
      float rs = rsum[mt][r];
#pragma unroll
      for (int mk = 1; mk < 16; mk <<= 1) rs += __shfl_xor(rs, mk);
      const float inv = 1.f / rs;
      const size_t orow = (size_t)(b * 1024 + qb * 128 + w * 32 + mt * 16 + qd * 4 + r);
#pragma unroll
      for (int dt = 0; dt < 4; dt++)
        o[orow * 768 + h * 64 + dt * 16 + l] = f2bf(oacc[mt][dt][r] * inv);
    }
}

// ---------------- launch ----------------
extern "C" void kernel_launch(void* const* d_in, const int* in_sizes, int n_in,
                              void* d_out, int out_size, void* d_ws, size_t ws_size,
                              hipStream_t stream) {
  const float* x      = (const float*)d_in[0];
  const float* c      = (const float*)d_in[1];
  const float* qkv_w  = (const float*)d_in[2];
  const float* qkv_b  = (const float*)d_in[3];
  const float* proj_w = (const float*)d_in[4];
  const float* proj_b = (const float*)d_in[5];
  const float* fc1_w  = (const float*)d_in[6];
  const float* fc1_b  = (const float*)d_in[7];
  const float* fc2_w  = (const float*)d_in[8];
  const float* fc2_b  = (const float*)d_in[9];
  const float* ada_w  = (const float*)d_in[10];
  const float* ada_b  = (const float*)d_in[11];
  float* out = (float*)d_out;

  char* ws = (char*)d_ws;
  float*          ada       = (float*)(ws + 0);                 //   147456 B
  unsigned short* qkv_w_bf  = (unsigned short*)(ws + 147456);   //  3538944 B
  unsigned short* proj_w_bf = (unsigned short*)(ws + 3686400);  //  1179648 B
  unsigned short* fc1_w_bf  = (unsigned short*)(ws + 4866048);  //  4718592 B
  unsigned short* fc2_w_bf  = (unsigned short*)(ws + 9584640);  //  4718592 B
  unsigned short* h_bf      = (unsigned short*)(ws + 14303232); // 12582912 B
  unsigned short* qk_bf     = (unsigned short*)(ws + 26886144); // 25165824 B
  unsigned short* vt_bf     = (unsigned short*)(ws + 52051968); // 12582912 B
  unsigned short* o_bf      = (unsigned short*)(ws + 64634880); // 12582912 B
  unsigned short* x1_bf     = (unsigned short*)(ws + 77217792); // 12582912 B -> 89800704
  unsigned short* f1_bf     = qk_bf;  // aliases qk+vt+o (all dead by fc1)

  // prologue: weight conversions + ada in one launch
  k_prologue<<<6984, 256, 0, stream>>>((const float4*)qkv_w, (ushort4*)qkv_w_bf,
                                       (const float4*)proj_w, (ushort4*)proj_w_bf,
                                       (const float4*)fc1_w, (ushort4*)fc1_w_bf,
                                       (const float4*)fc2_w, (ushort4*)fc2_w_bf,
                                       c, ada_w, ada_b, ada);

  // h = modulate(LN(x), sh_msa, sc_msa)
  k_ln_mod<false><<<8192, 256, 0, stream>>>(x, ada, 0, 768, h_bf);

  // qkv = h @ qkv_w.T + qkv_b  -> qk_bf + vt_bf (V pre-transposed)  [16x16 path]
  k_gemm16<0, 128><<<18 * 64, 256, 0, stream>>>(h_bf, qkv_w_bf, qkv_b, 2304, 768, 18,
                                                nullptr, nullptr, nullptr, 0,
                                                nullptr, qk_bf, vt_bf);

  // attention
  k_attn<<<dim3(8, 12, 8), 256, 0, stream>>>(qk_bf, vt_bf, o_bf);

  // x1 = bf16(x + g_msa * (o @ proj_w.T + proj_b))  [32x32 path]
  k_gemm32<1, 64><<<12 * 64, 256, 0, stream>>>(o_bf, proj_w_bf, proj_b, 768, 768, 12,
                                               x, nullptr, ada, 1536,
                                               nullptr, x1_bf, nullptr);

  // h2 = modulate(LN(x1), sh_mlp, sc_mlp)
  k_ln_mod<true><<<8192, 256, 0, stream>>>(x1_bf, ada, 2304, 3072, h_bf);

  // f1 = gelu(h2 @ fc1_w.T + fc1_b)  [32x32 path]
  k_gemm32<2, 128><<<24 * 64, 256, 0, stream>>>(h_bf, fc1_w_bf, fc1_b, 3072, 768, 24,
                                                nullptr, nullptr, nullptr, 0,
                                                nullptr, f1_bf, nullptr);

  // out = x1 + g_mlp * (f1 @ fc2_w.T + fc2_b)  [32x32 path]
  k_gemm32<3, 64><<<12 * 64, 256, 0, stream>>>(f1_bf, fc2_w_bf, fc2_b, 768, 3072, 12,
                                               nullptr, x1_bf, ada, 3840,
                                               out, nullptr, nullptr);
}

// Round 10
// 394.393 us; speedup vs baseline: 1.0650x; 1.0650x over previous
//
#include <hip/hip_runtime.h>
#include <hip/hip_bf16.h>
#include <math.h>

typedef __attribute__((ext_vector_type(8))) short bf16x8;
typedef __attribute__((ext_vector_type(4))) float f32x4;
typedef __attribute__((ext_vector_type(16))) float f32x16;

__device__ __forceinline__ unsigned short f2bf(float f) {
  union { float f; unsigned int u; } v; v.f = f;
  unsigned int u = v.u;
  u += 0x7fffu + ((u >> 16) & 1u);   // RNE
  return (unsigned short)(u >> 16);
}

// packed RNE pair -> v_cvt_pk_bf16_f32 (lo in bits 0..15)
__device__ __forceinline__ unsigned int f2bf2(float lo, float hi) {
  __hip_bfloat162 h = __float22bfloat162_rn(make_float2(lo, hi));
  union { __hip_bfloat162 h; unsigned int u; } v; v.h = h;
  return v.u;
}

__device__ __forceinline__ float bf2f(unsigned short h) {
  union { unsigned int u; float f; } v; v.u = ((unsigned int)h) << 16;
  return v.f;
}

// async global->LDS, 16B per lane; LDS dest = wave-uniform base + lane*16
__device__ __forceinline__ void gl2l16(const unsigned short* g, unsigned short* l) {
  __builtin_amdgcn_global_load_lds(
      (const __attribute__((address_space(1))) unsigned int*)g,
      (__attribute__((address_space(3))) unsigned int*)l, 16, 0, 0);
}

// fast tanh-form GELU: v * sigmoid(1.5957691*v + 0.0713548*v^3)
__device__ __forceinline__ float gelu_fast(float v) {
  float arg = v * (1.59576912f + 0.07135481f * v * v);
  return v / (1.f + __expf(-arg));
}

// ---------------- prologue: weight conversions (blocks 0..6911) + ada (6912..6983) ----
__global__ __launch_bounds__(256) void k_prologue(
    const float4* __restrict__ s0, ushort4* __restrict__ d0,
    const float4* __restrict__ s1, ushort4* __restrict__ d1,
    const float4* __restrict__ s2, ushort4* __restrict__ d2,
    const float4* __restrict__ s3, ushort4* __restrict__ d3,
    const float* __restrict__ c, const float* __restrict__ ada_w,
    const float* __restrict__ ada_b, float* __restrict__ ada) {
  __shared__ float smem[8 * 768 + 4 * 64 * 8];
  const int t = threadIdx.x;
  const int id = blockIdx.x;
  if (id < 6912) {
    int i = id * 256 + t;
    const float4* s; ushort4* d; int off;
    if (i < 442368) { s = s0; d = d0; off = i; }
    else if (i < 589824) { s = s1; d = d1; off = i - 442368; }
    else if (i < 1179648) { s = s2; d = d2; off = i - 589824; }
    else { s = s3; d = d3; off = i - 1179648; }
    float4 f = s[off];
    union { unsigned int u[2]; ushort4 o; } pk;
    pk.u[0] = f2bf2(f.x, f.y);
    pk.u[1] = f2bf2(f.z, f.w);
    d[off] = pk.o;
    return;
  }
  // ---- ada path ----
  float* sc = smem;
  float* red = smem + 8 * 768;  // [4][64][8]
  for (int i = t; i < 8 * 768; i += 256) {
    float v = c[i];
    sc[i] = v / (1.f + __expf(-v));
  }
  __syncthreads();
  const int cl = t & 63, ks = t >> 6;
  const int col = (id - 6912) * 64 + cl;
  float acc[8];
#pragma unroll
  for (int b = 0; b < 8; b++) acc[b] = 0.f;
  const float* wr = ada_w + (size_t)col * 768 + ks * 192;
  for (int k = 0; k < 192; k += 4) {
    float4 w = *(const float4*)&wr[k];
    const int kk = ks * 192 + k;
#pragma unroll
    for (int b = 0; b < 8; b++) {
      acc[b] += sc[b * 768 + kk] * w.x + sc[b * 768 + kk + 1] * w.y +
                sc[b * 768 + kk + 2] * w.z + sc[b * 768 + kk + 3] * w.w;
    }
  }
#pragma unroll
  for (int b = 0; b < 8; b++) red[(ks * 64 + cl) * 8 + b] = acc[b];
  __syncthreads();
  if (ks == 0) {
    const float bj = ada_b[col];
#pragma unroll
    for (int b = 0; b < 8; b++)
      ada[b * 4608 + col] = red[(0 * 64 + cl) * 8 + b] + red[(1 * 64 + cl) * 8 + b] +
                            red[(2 * 64 + cl) * 8 + b] + red[(3 * 64 + cl) * 8 + b] + bj;
  }
}

// ---------------- LayerNorm + modulate -> bf16 (fp32 or bf16 input) ----------------
template <bool BF>
__global__ __launch_bounds__(256) void k_ln_mod(const void* __restrict__ xin,
                                                const float* __restrict__ ada,
                                                int sh_off, int sc_off,
                                                unsigned short* __restrict__ h) {
  const int row = blockIdx.x, t = threadIdx.x, b = row >> 10;
  float v0, v1, v2;
  if (BF) {
    const unsigned short* xr = (const unsigned short*)xin + (size_t)row * 768;
    v0 = bf2f(xr[t]); v1 = bf2f(xr[t + 256]); v2 = bf2f(xr[t + 512]);
  } else {
    const float* xr = (const float*)xin + (size_t)row * 768;
    v0 = xr[t]; v1 = xr[t + 256]; v2 = xr[t + 512];
  }
  float s = v0 + v1 + v2;
  float ss = v0 * v0 + v1 * v1 + v2 * v2;
#pragma unroll
  for (int m = 1; m < 64; m <<= 1) {
    s += __shfl_xor(s, m);
    ss += __shfl_xor(ss, m);
  }
  __shared__ float red[8];
  if ((t & 63) == 0) { red[t >> 6] = s; red[4 + (t >> 6)] = ss; }
  __syncthreads();
  const float S = red[0] + red[1] + red[2] + red[3];
  const float SS = red[4] + red[5] + red[6] + red[7];
  const float mean = S * (1.f / 768.f);
  const float var = SS * (1.f / 768.f) - mean * mean;
  const float inv = rsqrtf(var + 1e-6f);
  const float* sh = ada + b * 4608 + sh_off;
  const float* scp = ada + b * 4608 + sc_off;
  unsigned short* hr = h + (size_t)row * 768;
  float vv[3] = {v0, v1, v2};
#pragma unroll
  for (int i = 0; i < 3; i++) {
    int cx = t + i * 256;
    float hh = (vv[i] - mean) * inv;
    hh = hh * (1.f + scp[cx]) + sh[cx];
    hr[cx] = f2bf(hh);
  }
}

// ---------------- GEMM v16: 16x16x32 MFMA — qkv (EPI 0) ----------------
// Epilogue: q region pre-scaled by 0.125 (attn drops its per-score mul);
// V written transposed via one ushort4 store (4 consecutive nn rows).
template <int EPI, int TN>
__global__ __launch_bounds__(256) void k_gemm16(const unsigned short* __restrict__ A,
                                                const unsigned short* __restrict__ B,
                                                const float* __restrict__ bias,
                                                int N, int K, int nbx,
                                                const float* __restrict__ residf,
                                                const unsigned short* __restrict__ residb,
                                                const float* __restrict__ ada, int goff,
                                                float* __restrict__ outf,
                                                unsigned short* __restrict__ outb,
                                                unsigned short* __restrict__ vt) {
  constexpr int MI = (TN == 128) ? 4 : 2;
  __shared__ __align__(16) unsigned short Asm[2][128 * 32];
  __shared__ __align__(16) unsigned short Bsm[2][TN * 32];
  const int t = threadIdx.x;
  const int w = t >> 6, lane = t & 63, l = lane & 15, qd = lane >> 4;

  const int id = blockIdx.x;
  const int xcd = id & 7, jj = id >> 3;
  const int jm = jj / nbx;
  const int bmi = xcd + (jm << 3);
  const int bni = jj - jm * nbx;
  const int bn = bni * TN, bm = bmi * 128;

  const int wm = (TN == 128) ? (w >> 1) * 64 : w * 32;
  const int wn = (TN == 128) ? (w & 1) * 64 : 0;

  const int srow = t >> 2;
  const int scol = ((t & 3) ^ ((srow >> 1) & 3)) * 8;
  const unsigned short* Ap0 = A + (size_t)(bm + srow) * K + scol;
  const unsigned short* Ap1 = A + (size_t)(bm + 64 + srow) * K + scol;
  const unsigned short* Bp0 = B + (size_t)(bn + srow) * K + scol;
  const unsigned short* Bp1 = B + (size_t)(bn + 64 + srow) * K + scol;

  f32x4 acc[MI][4];
#pragma unroll
  for (int i = 0; i < MI; i++)
#pragma unroll
    for (int j = 0; j < 4; j++) acc[i][j] = {0.f, 0.f, 0.f, 0.f};

  const int swz = (l >> 1) & 3;

  for (int k0 = 0; k0 < K; k0 += 64) {
#pragma unroll
    for (int s = 0; s < 2; s++) {
      gl2l16(Ap0 + k0 + 32 * s, &Asm[s][w * 512]);
      gl2l16(Ap1 + k0 + 32 * s, &Asm[s][2048 + w * 512]);
      gl2l16(Bp0 + k0 + 32 * s, &Bsm[s][w * 512]);
      if (TN == 128) gl2l16(Bp1 + k0 + 32 * s, &Bsm[s][2048 + w * 512]);
    }
    __syncthreads();
#pragma unroll
    for (int s = 0; s < 2; s++) {
      bf16x8 af[MI], bfr[4];
#pragma unroll
      for (int i = 0; i < MI; i++)
        af[i] = *(const bf16x8*)&Asm[s][(wm + i * 16 + l) * 32 + ((qd ^ swz) << 3)];
#pragma unroll
      for (int j = 0; j < 4; j++)
        bfr[j] = *(const bf16x8*)&Bsm[s][(wn + j * 16 + l) * 32 + ((qd ^ swz) << 3)];
#pragma unroll
      for (int i = 0; i < MI; i++)
#pragma unroll
        for (int j = 0; j < 4; j++)
          acc[i][j] = __builtin_amdgcn_mfma_f32_16x16x32_bf16(af[i], bfr[j], acc[i][j], 0, 0, 0);
    }
    __syncthreads();
  }

  const int bb = bm >> 10;  // 128-row tile never crosses a batch boundary
#pragma unroll
  for (int i = 0; i < MI; i++) {
#pragma unroll
    for (int j = 0; j < 4; j++) {
      const int gn = bn + wn + j * 16 + l;
      const float bv = bias[gn];
      const int gm0 = bm + wm + i * 16 + qd * 4;
      float vv[4];
#pragma unroll
      for (int r = 0; r < 4; r++) vv[r] = acc[i][j][r] + bv;
      if (EPI == 0) {
        if (gn < 1536) {
          if (gn < 768) {  // uniform per block (768 % 128 == 0): pre-scale Q
#pragma unroll
            for (int r = 0; r < 4; r++) vv[r] *= 0.125f;
          }
          const unsigned int p01 = f2bf2(vv[0], vv[1]);
          const unsigned int p23 = f2bf2(vv[2], vv[3]);
          outb[(size_t)gm0 * 1536 + gn] = (unsigned short)(p01 & 0xffff);
          outb[(size_t)(gm0 + 1) * 1536 + gn] = (unsigned short)(p01 >> 16);
          outb[(size_t)(gm0 + 2) * 1536 + gn] = (unsigned short)(p23 & 0xffff);
          outb[(size_t)(gm0 + 3) * 1536 + gn] = (unsigned short)(p23 >> 16);
        } else {
          const int hh = (gn - 1536) >> 6, dd = (gn - 1536) & 63;
          const int nn = gm0 & 1023;  // 4 consecutive rows -> contiguous, 8B-aligned
          union { unsigned int u[2]; ushort4 o; } pk;
          pk.u[0] = f2bf2(vv[0], vv[1]);
          pk.u[1] = f2bf2(vv[2], vv[3]);
          *(ushort4*)&vt[(((size_t)bb * 12 + hh) * 64 + dd) * 1024 + nn] = pk.o;
        }
      } else if (EPI == 2) {
#pragma unroll
        for (int r = 0; r < 4; r++)
          outb[(size_t)(gm0 + r) * N + gn] = f2bf(gelu_fast(vv[r]));
      } else {
        const float g = ada[bb * 4608 + goff + gn];
#pragma unroll
        for (int r = 0; r < 4; r++) {
          if (EPI == 1)
            outb[(size_t)(gm0 + r) * 768 + gn] =
                f2bf(residf[(size_t)(gm0 + r) * 768 + gn] + g * vv[r]);
          else
            outf[(size_t)(gm0 + r) * 768 + gn] =
                bf2f(residb[(size_t)(gm0 + r) * 768 + gn]) + g * vv[r];
        }
      }
    }
  }
}

// ---------------- GEMM v32: 32x32x16 MFMA — proj/fc1/fc2 ----------------
template <int EPI, int TN>
__global__ __launch_bounds__(256) void k_gemm32(const unsigned short* __restrict__ A,
                                                const unsigned short* __restrict__ B,
                                                const float* __restrict__ bias,
                                                int N, int K, int nbx,
                                                const float* __restrict__ residf,
                                                const unsigned short* __restrict__ residb,
                                                const float* __restrict__ ada, int goff,
                                                float* __restrict__ outf,
                                                unsigned short* __restrict__ outb,
                                                unsigned short* __restrict__ vt) {
  constexpr int NMT = (TN == 128) ? 2 : 1;   // 32-row m-tiles per wave
  __shared__ __align__(16) unsigned short Asm[2][128 * 32];
  __shared__ __align__(16) unsigned short Bsm[2][TN * 32];
  const int t = threadIdx.x;
  const int w = t >> 6, lane = t & 63;
  const int ln31 = lane & 31, half = lane >> 5;

  const int id = blockIdx.x;
  const int xcd = id & 7, jj = id >> 3;
  const int jm = jj / nbx;
  const int bmi = xcd + (jm << 3);
  const int bni = jj - jm * nbx;
  const int bn = bni * TN, bm = bmi * 128;

  const int wm = (TN == 128) ? (w >> 1) * 64 : w * 32;
  const int wn = (TN == 128) ? (w & 1) * 64 : 0;

  const int srow = t >> 2;
  const int scol = ((t & 3) ^ ((srow >> 1) & 3)) * 8;
  const unsigned short* Ap0 = A + (size_t)(bm + srow) * K + scol;
  const unsigned short* Ap1 = A + (size_t)(bm + 64 + srow) * K + scol;
  const unsigned short* Bp0 = B + (size_t)(bn + srow) * K + scol;
  const unsigned short* Bp1 = B + (size_t)(bn + 64 + srow) * K + scol;

  f32x16 acc[NMT][2];
#pragma unroll
  for (int i = 0; i < NMT; i++)
#pragma unroll
    for (int j = 0; j < 2; j++)
#pragma unroll
      for (int r = 0; r < 16; r++) acc[i][j][r] = 0.f;

  const int swz = (ln31 >> 1) & 3;

  for (int k0 = 0; k0 < K; k0 += 64) {
#pragma unroll
    for (int s = 0; s < 2; s++) {
      gl2l16(Ap0 + k0 + 32 * s, &Asm[s][w * 512]);
      gl2l16(Ap1 + k0 + 32 * s, &Asm[s][2048 + w * 512]);
      gl2l16(Bp0 + k0 + 32 * s, &Bsm[s][w * 512]);
      if (TN == 128) gl2l16(Bp1 + k0 + 32 * s, &Bsm[s][2048 + w * 512]);
    }
    __syncthreads();
#pragma unroll
    for (int s = 0; s < 4; s++) {          // 4 k-steps of 16
      const int sb = s >> 1;
      const int chunk = (s & 1) * 2 + half;
      const int coff = ((chunk ^ swz) << 3);
      bf16x8 af[NMT], bfr[2];
#pragma unroll
      for (int i = 0; i < NMT; i++)
        af[i] = *(const bf16x8*)&Asm[sb][(wm + i * 32 + ln31) * 32 + coff];
#pragma unroll
      for (int j = 0; j < 2; j++)
        bfr[j] = *(const bf16x8*)&Bsm[sb][(wn + j * 32 + ln31) * 32 + coff];
#pragma unroll
      for (int i = 0; i < NMT; i++)
#pragma unroll
        for (int j = 0; j < 2; j++)
          acc[i][j] = __builtin_amdgcn_mfma_f32_32x32x16_bf16(af[i], bfr[j], acc[i][j], 0, 0, 0);
    }
    __syncthreads();
  }

  const int bb = bm >> 10;  // constant per block
#pragma unroll
  for (int i = 0; i < NMT; i++) {
#pragma unroll
    for (int j = 0; j < 2; j++) {
      const int gn = bn + wn + j * 32 + ln31;
      const float bv = bias[gn];
      const float g = (EPI == 2) ? 0.f : ada[bb * 4608 + goff + gn];
#pragma unroll
      for (int reg = 0; reg < 16; reg++) {
        const int gm = bm + wm + i * 32 + (reg & 3) + 8 * (reg >> 2) + 4 * half;
        float v = acc[i][j][reg] + bv;
        if (EPI == 1) {
          outb[(size_t)gm * 768 + gn] =
              f2bf(residf[(size_t)gm * 768 + gn] + g * v);
        } else if (EPI == 2) {
          outb[(size_t)gm * N + gn] = f2bf(gelu_fast(v));
        } else {
          outf[(size_t)gm * 768 + gn] =
              bf2f(residb[(size_t)gm * 768 + gn]) + g * v;
        }
      }
    }
  }
}

// ---------------- Attention: 128 Q rows per block, no-max softmax ----------------
// qk: (8192,1536) bf16 [q(pre-scaled 0.125)|k]; vt: (8,12,64,1024); o: (8192,768)
__global__ __launch_bounds__(256) void k_attn(const unsigned short* __restrict__ qk,
                                              const unsigned short* __restrict__ vt,
                                              unsigned short* __restrict__ o) {
  __shared__ __align__(16) unsigned short Ksm[64 * 64];
  __shared__ __align__(16) unsigned short Vsm[64 * 64];
  __shared__ __align__(16) unsigned short Psm[128 * 76];
  const int t = threadIdx.x;
  const int qb = blockIdx.x, h = blockIdx.y, b = blockIdx.z;
  const int w = t >> 6, lane = t & 63, l = lane & 15, qd = lane >> 4;

  const size_t qrow0 = (size_t)(b * 1024 + qb * 128 + w * 32 + l);
  bf16x8 qf[2][2];
#pragma unroll
  for (int mt = 0; mt < 2; mt++)
#pragma unroll
    for (int ks = 0; ks < 2; ks++)
      qf[mt][ks] = *(const bf16x8*)&qk[(qrow0 + mt * 16) * 1536 + h * 64 + ks * 32 + qd * 8];

  f32x4 oacc[2][4];
  float rsum[2][4];
#pragma unroll
  for (int mt = 0; mt < 2; mt++)
#pragma unroll
    for (int j2 = 0; j2 < 4; j2++) { oacc[mt][j2] = {0.f, 0.f, 0.f, 0.f}; rsum[mt][j2] = 0.f; }

  const size_t kbase = (size_t)b * 1024 * 1536 + 768 + h * 64;
  const size_t vbase = ((size_t)(b * 12 + h)) * 64 * 1024;

  const int srw8 = lane >> 3, schk = lane & 7;
  const int swz = (l >> 1) & 7;

  for (int k0 = 0; k0 < 1024; k0 += 64) {
#pragma unroll
    for (int c = 0; c < 2; c++) {
      const int row = c * 32 + w * 8 + srw8;
      const int sc = (schk ^ ((row >> 1) & 7)) * 8;
      gl2l16(&qk[kbase + (size_t)(k0 + row) * 1536 + sc], &Ksm[(c * 32 + w * 8) * 64]);
      gl2l16(&vt[vbase + (size_t)row * 1024 + k0 + sc], &Vsm[(c * 32 + w * 8) * 64]);
    }
    __syncthreads();

    bf16x8 kf[4][2];
#pragma unroll
    for (int ct = 0; ct < 4; ct++)
#pragma unroll
      for (int ks = 0; ks < 2; ks++)
        kf[ct][ks] = *(const bf16x8*)&Ksm[(ct * 16 + l) * 64 + (((ks * 4 + qd) ^ swz) << 3)];

#pragma unroll
    for (int mt = 0; mt < 2; mt++) {
      f32x4 s[4];
#pragma unroll
      for (int ct = 0; ct < 4; ct++) {
        f32x4 a = {0.f, 0.f, 0.f, 0.f};
        a = __builtin_amdgcn_mfma_f32_16x16x32_bf16(qf[mt][0], kf[ct][0], a, 0, 0, 0);
        a = __builtin_amdgcn_mfma_f32_16x16x32_bf16(qf[mt][1], kf[ct][1], a, 0, 0, 0);
        s[ct] = a;
      }
#pragma unroll
      for (int ct = 0; ct < 4; ct++) {
        float p[4];
#pragma unroll
        for (int r = 0; r < 4; r++) {
          p[r] = __expf(s[ct][r]);   // Q pre-scaled by 0.125 at qkv epilogue
          rsum[mt][r] += p[r];
        }
        const unsigned int p01 = f2bf2(p[0], p[1]);
        const unsigned int p23 = f2bf2(p[2], p[3]);
        const int pbase = (w * 32 + mt * 16 + qd * 4) * 76 + ct * 16 + l;
        Psm[pbase] = (unsigned short)(p01 & 0xffff);
        Psm[pbase + 76] = (unsigned short)(p01 >> 16);
        Psm[pbase + 152] = (unsigned short)(p23 & 0xffff);
        Psm[pbase + 228] = (unsigned short)(p23 >> 16);
      }
    }

    bf16x8 vf[4][2];
#pragma unroll
    for (int dt = 0; dt < 4; dt++)
#pragma unroll
      for (int ks = 0; ks < 2; ks++)
        vf[dt][ks] = *(const bf16x8*)&Vsm[(dt * 16 + l) * 64 + (((ks * 4 + qd) ^ swz) << 3)];
#pragma unroll
    for (int mt = 0; mt < 2; mt++) {
      bf16x8 pf0 = *(const bf16x8*)&Psm[(w * 32 + mt * 16 + l) * 76 + qd * 8];
      bf16x8 pf1 = *(const bf16x8*)&Psm[(w * 32 + mt * 16 + l) * 76 + 32 + qd * 8];
#pragma unroll
      for (int dt = 0; dt < 4; dt++) {
        oacc[mt][dt] = __builtin_amdgcn_mfma_f32_16x16x32_bf16(pf0, vf[dt][0], oacc[mt][dt], 0, 0, 0);
        oacc[mt][dt] = __builtin_amdgcn_mfma_f32_16x16x32_bf16(pf1, vf[dt][1], oacc[mt][dt], 0, 0, 0);
      }
    }
    __syncthreads();
  }

#pragma unroll
  for (int mt = 0; mt < 2; mt++)
#pragma unroll
    for (int r = 0; r < 4; r++) {
      float rs = rsum[mt][r];
#pragma unroll
      for (int mk = 1; mk < 16; mk <<= 1) rs += __shfl_xor(rs, mk);
      const float inv = 1.f / rs;
      const size_t orow = (size_t)(b * 1024 + qb * 128 + w * 32 + mt * 16 + qd * 4 + r);
      const unsigned int o01 = f2bf2(oacc[0 + mt][0][r] * inv, oacc[mt][1][r] * inv);
      const unsigned int o23 = f2bf2(oacc[mt][2][r] * inv, oacc[mt][3][r] * inv);
      unsigned short* op = &o[orow * 768 + h * 64 + l];
      op[0] = (unsigned short)(o01 & 0xffff);
      op[16] = (unsigned short)(o01 >> 16);
      op[32] = (unsigned short)(o23 & 0xffff);
      op[48] = (unsigned short)(o23 >> 16);
    }
}

// ---------------- launch ----------------
extern "C" void kernel_launch(void* const* d_in, const int* in_sizes, int n_in,
                              void* d_out, int out_size, void* d_ws, size_t ws_size,
                              hipStream_t stream) {
  const float* x      = (const float*)d_in[0];
  const float* c      = (const float*)d_in[1];
  const float* qkv_w  = (const float*)d_in[2];
  const float* qkv_b  = (const float*)d_in[3];
  const float* proj_w = (const float*)d_in[4];
  const float* proj_b = (const float*)d_in[5];
  const float* fc1_w  = (const float*)d_in[6];
  const float* fc1_b  = (const float*)d_in[7];
  const float* fc2_w  = (const float*)d_in[8];
  const float* fc2_b  = (const float*)d_in[9];
  const float* ada_w  = (const float*)d_in[10];
  const float* ada_b  = (const float*)d_in[11];
  float* out = (float*)d_out;

  char* ws = (char*)d_ws;
  float*          ada       = (float*)(ws + 0);                 //   147456 B
  unsigned short* qkv_w_bf  = (unsigned short*)(ws + 147456);   //  3538944 B
  unsigned short* proj_w_bf = (unsigned short*)(ws + 3686400);  //  1179648 B
  unsigned short* fc1_w_bf  = (unsigned short*)(ws + 4866048);  //  4718592 B
  unsigned short* fc2_w_bf  = (unsigned short*)(ws + 9584640);  //  4718592 B
  unsigned short* h_bf      = (unsigned short*)(ws + 14303232); // 12582912 B
  unsigned short* qk_bf     = (unsigned short*)(ws + 26886144); // 25165824 B
  unsigned short* vt_bf     = (unsigned short*)(ws + 52051968); // 12582912 B
  unsigned short* o_bf      = (unsigned short*)(ws + 64634880); // 12582912 B
  unsigned short* x1_bf     = (unsigned short*)(ws + 77217792); // 12582912 B -> 89800704
  unsigned short* f1_bf     = qk_bf;  // aliases qk+vt+o (all dead by fc1)

  // prologue: weight conversions + ada in one launch
  k_prologue<<<6984, 256, 0, stream>>>((const float4*)qkv_w, (ushort4*)qkv_w_bf,
                                       (const float4*)proj_w, (ushort4*)proj_w_bf,
                                       (const float4*)fc1_w, (ushort4*)fc1_w_bf,
                                       (const float4*)fc2_w, (ushort4*)fc2_w_bf,
                                       c, ada_w, ada_b, ada);

  // h = modulate(LN(x), sh_msa, sc_msa)
  k_ln_mod<false><<<8192, 256, 0, stream>>>(x, ada, 0, 768, h_bf);

  // qkv = h @ qkv_w.T + qkv_b  -> qk_bf (q pre-scaled) + vt_bf (V transposed)
  k_gemm16<0, 128><<<18 * 64, 256, 0, stream>>>(h_bf, qkv_w_bf, qkv_b, 2304, 768, 18,
                                                nullptr, nullptr, nullptr, 0,
                                                nullptr, qk_bf, vt_bf);

  // attention
  k_attn<<<dim3(8, 12, 8), 256, 0, stream>>>(qk_bf, vt_bf, o_bf);

  // x1 = bf16(x + g_msa * (o @ proj_w.T + proj_b))  [32x32 path]
  k_gemm32<1, 64><<<12 * 64, 256, 0, stream>>>(o_bf, proj_w_bf, proj_b, 768, 768, 12,
                                               x, nullptr, ada, 1536,
                                               nullptr, x1_bf, nullptr);

  // h2 = modulate(LN(x1), sh_mlp, sc_mlp)
  k_ln_mod<true><<<8192, 256, 0, stream>>>(x1_bf, ada, 2304, 3072, h_bf);

  // f1 = gelu(h2 @ fc1_w.T + fc1_b)  [32x32 path]
  k_gemm32<2, 128><<<24 * 64, 256, 0, stream>>>(h_bf, fc1_w_bf, fc1_b, 3072, 768, 24,
                                                nullptr, nullptr, nullptr, 0,
                                                nullptr, f1_bf, nullptr);

  // out = x1 + g_mlp * (f1 @ fc2_w.T + fc2_b)  [32x32 path]
  k_gemm32<3, 64><<<12 * 64, 256, 0, stream>>>(f1_bf, fc2_w_bf, fc2_b, 768, 3072, 12,
                                               nullptr, x1_bf, ada, 3840,
                                               out, nullptr, nullptr);
}